// Round 7
// baseline (531.617 us; speedup 1.0000x reference)
//
#include <hip/hip_runtime.h>
#include <math.h>

typedef int    intx8    __attribute__((ext_vector_type(8)));   // 8 dwords = 32 fp8
typedef float  floatx16 __attribute__((ext_vector_type(16)));  // MFMA 32x32 C/D

#define N_ROWS 8192
#define H_DIM  1024
#define UNITS  68            // 64 data k-units + 1 bias-aug unit + 3 zero-pad (BK alignment)
#define V_DIM  32000
#define V_PAD  32768
#define IGNORE_INDEX (-100)

#define S_SPLITS 16          // 16 splits x 16 tiles x 128 cols = 32768
#define TILES_PER_SPLIT 16
#define BM 256
#define BN 128
#define KSTEPS 17            // 17 steps of BK=64 (4 units) = 68 units
#define NSTEPS (TILES_PER_SPLIT * KSTEPS)   // 272

#define LOG2E 1.4426950408889634f
#define LN2   0.6931471805599453f

// ---------- fused prep ----------
// fp32 [R][1024] -> fp8 e4m3 "unit-transposed" [68 k-units][Rstride][16B].
__device__ __forceinline__ void conv_one(const float* __restrict__ in,
                                         unsigned char* __restrict__ out,
                                         int r, int u, int Rstride, float scale) {
  const float4* src = (const float4*)(in + (size_t)r * H_DIM + u * 16);
  uint4 res;
#pragma unroll
  for (int j = 0; j < 4; ++j) {
    const float4 v = src[j];
    int p = __builtin_amdgcn_cvt_pk_fp8_f32(v.x * scale, v.y * scale, 0, false);
    p = __builtin_amdgcn_cvt_pk_fp8_f32(v.z * scale, v.w * scale, p, true);
    ((int*)&res)[j] = p;
  }
  *(uint4*)(out + ((size_t)u * Rstride + r) * 16) = res;
}

// Ranges: W convert (8000) | x convert (2048) | W bias-aug unit 64 (128) |
// x aug unit 64 (32) | x zero units 65-67 (96) | exact tgt logits (2048).
// Bias folded into GEMM: W[.,k=1024] = bias*log2e (pad rows: -448 = fp8 0xFE,
// killing pad cols: acc_pad <= -350 -> 2^acc = 0). x[.,1024] = 1.0 (fp8 0x38).
// W units 65-67 left poisoned: x is zero there, 0*poison = 0 (e4m3fn has no inf).
__global__ __launch_bounds__(256) void prep_all(const float* __restrict__ x,
                                                const float* __restrict__ wgt,
                                                const float* __restrict__ bias,
                                                const int* __restrict__ target,
                                                unsigned char* __restrict__ xs8,
                                                unsigned char* __restrict__ ws8,
                                                float* __restrict__ tgt_logit) {
  const int bid = blockIdx.x;
  const int tid = threadIdx.x;
  if (bid < 8000) {                         // W units 0..63 (pad rows stay poisoned: killed by -448 aug)
    conv_one(wgt, ws8, (bid % 125) * 256 + tid, bid / 125, V_PAD, 1.0f);
  } else if (bid < 10048) {                 // x units 0..63, pre-scaled by log2e
    const int b = bid - 8000;
    conv_one(x, xs8, (b % 32) * 256 + tid, b / 32, N_ROWS, LOG2E);
  } else if (bid < 10176) {                 // W aug unit 64: byte0 = fp8(bias*log2e) or -448 kill
    const int r = (bid - 10048) * 256 + tid;
    uint4 z = {0, 0, 0, 0};
    unsigned char b0;
    if (r < V_DIM) {
      const int p = __builtin_amdgcn_cvt_pk_fp8_f32(bias[r] * LOG2E, 0.f, 0, false);
      b0 = (unsigned char)(p & 0xFF);
    } else {
      b0 = 0xFE;                            // -448 (e4m3 max-negative)
    }
    ((unsigned char*)&z)[0] = b0;
    *(uint4*)(ws8 + ((size_t)64 * V_PAD + r) * 16) = z;
  } else if (bid < 10208) {                 // x aug unit 64: [1.0, 0 x15]
    const int r = (bid - 10176) * 256 + tid;
    uint4 z = {0, 0, 0, 0};
    ((unsigned char*)&z)[0] = 0x38;         // fp8 e4m3 1.0
    *(uint4*)(xs8 + ((size_t)64 * N_ROWS + r) * 16) = z;
  } else if (bid < 10304) {                 // x zero units 65..67
    const int b = bid - 10208;
    const int u = 65 + b / 32;
    const int r = (b % 32) * 256 + tid;
    const uint4 z = {0, 0, 0, 0};
    *(uint4*)(xs8 + ((size_t)u * N_ROWS + r) * 16) = z;
  } else {                                  // tgt: one wave per row, exact fp32
    const int r = (bid - 10304) * 4 + (tid >> 6);
    const int lane = tid & 63;
    const int t = target[r];
    const int tt = (t == IGNORE_INDEX) ? 0 : t;
    const float4* xr = (const float4*)(x + (size_t)r * H_DIM);
    const float4* wr = (const float4*)(wgt + (size_t)tt * H_DIM);
    float acc = 0.f;
#pragma unroll
    for (int i = 0; i < 4; ++i) {
      const float4 a = xr[lane + i * 64];
      const float4 b = wr[lane + i * 64];
      acc += a.x * b.x + a.y * b.y + a.z * b.z + a.w * b.w;
    }
#pragma unroll
    for (int off = 32; off >= 1; off >>= 1) acc += __shfl_xor(acc, off, 64);
    if (lane == 0) tgt_logit[r] = acc + bias[tt];
  }
}

// ---------- main fused GEMM + sumexp ----------
// Software pipeline with raw s_barrier + explicit vmcnt (the structure
// __syncthreads' mandatory vmcnt(0) cannot express):
//   per step: [waitcnt vmcnt(2) lgkmcnt(0); s_barrier] -> issue A(f+1)[4],
//   B(f+2)[2] -> ds_read(f) -> 8x MFMA.
// Queue at each barrier: [B(f+1), A(f+1), B(f+2)] -> vmcnt(2) waits exactly
// the loads that have had >=1 full MFMA phase in flight; lgkmcnt(0) pins my
// ds_reads so post-barrier issues can't overwrite a buffer still being read.
// A: 2 buffers (1-step lead), B: 3 buffers (2-step lead). LDS 56KB, 2 blk/CU.
__global__ __launch_bounds__(256, 2) void flce_main(const unsigned char* __restrict__ xs,
                                                    const unsigned char* __restrict__ wsb,
                                                    float* __restrict__ partials) {
  __shared__ __align__(16) unsigned char smA[2][4 * 256 * 16];  // 2 x 16KB
  __shared__ __align__(16) unsigned char smB[3][4 * 128 * 16];  // 3 x 8KB

  const int tid  = threadIdx.x;
  const int lane = tid & 63;
  const int w    = tid >> 6;      // wave 0..3: rows [w*64, w*64+64)
  const int l31  = lane & 31;
  const int half = lane >> 5;     // k-half within MFMA (32 k each)
  const int wr   = w * 64;
  const int row0 = blockIdx.x * BM;
  const int n0base = blockIdx.y * TILES_PER_SPLIT * BN;

  float l_state[32];
#pragma unroll
  for (int i = 0; i < 32; ++i) l_state[i] = 0.f;

  floatx16 acc[2][4];
#pragma unroll
  for (int mb = 0; mb < 2; ++mb)
#pragma unroll
    for (int nb = 0; nb < 4; ++nb)
#pragma unroll
      for (int i = 0; i < 16; ++i) acc[mb][nb][i] = 0.f;

  // A: one BK=64 step (4 units), 16 x 1KB wave-DMAs split over 4 waves.
  auto issue_A = [&](int k, int p) {
    const int ub = k * 4;
#pragma unroll
    for (int j = 0; j < 4; ++j) {
      const int c = j * 4 + w;
      const int u = c >> 2;
      const int rb = c & 3;
      __builtin_amdgcn_global_load_lds(
          (const __attribute__((address_space(1))) void*)(xs + ((size_t)(ub + u) * N_ROWS + row0 + rb * 64 + lane) * 16),
          (__attribute__((address_space(3))) void*)(smA[p] + ((u * 256 + rb * 64 + lane) * 16)),
          16, 0, 0);
    }
  };
  // B: one step, 8 x 1KB wave-DMAs split over 4 waves.
  auto issue_B = [&](int k, int n0, int p) {
    const int ub = k * 4;
#pragma unroll
    for (int j = 0; j < 2; ++j) {
      const int c = j * 4 + w;
      const int u = c >> 1;
      const int rb = c & 1;
      __builtin_amdgcn_global_load_lds(
          (const __attribute__((address_space(1))) void*)(wsb + ((size_t)(ub + u) * V_PAD + n0 + rb * 64 + lane) * 16),
          (__attribute__((address_space(3))) void*)(smB[p] + ((u * 128 + rb * 64 + lane) * 16)),
          16, 0, 0);
    }
  };

  // Prologue. Issue order matters for vmcnt queue: [B0, A0, B1].
  issue_B(0, n0base, 0);
  issue_A(0, 0);
  issue_B(1, n0base, 1);

  int kk = 0;                    // k-index of the read step (0..16; 16 = aug/epilogue step)
  int kA = 1;                    // k of next A issue
  int kB = 2, n0B = n0base;      // k and n0 of next B issue
  int pB = 0, pBi = 2;           // B read / issue buffer
  int sidx_out = 0;              // tiles completed (for epilogue bookkeeping not needed; partials use blockIdx.y)

  const int ua = half * 2;       // this lane-half's 2 k-units within the 4-unit buffer

#pragma unroll 1
  for (int f = 0; f < NSTEPS; ++f) {
    if (f == NSTEPS - 1)
      asm volatile("s_waitcnt vmcnt(0) lgkmcnt(0)\ns_barrier" ::: "memory");
    else
      asm volatile("s_waitcnt vmcnt(2) lgkmcnt(0)\ns_barrier" ::: "memory");

    const int pA = f & 1;
    if (f + 1 < NSTEPS) {
      issue_A(kA, pA ^ 1);
      kA = (kA == KSTEPS - 1) ? 0 : kA + 1;
    }
    if (f + 2 < NSTEPS) {
      issue_B(kB, n0B, pBi);
      if (++kB == KSTEPS) { kB = 0; n0B += BN; }
      if (++pBi == 3) pBi = 0;
    }

    union { intx8 v; uint4 q[2]; } a[2], b[4];
#pragma unroll
    for (int mb = 0; mb < 2; ++mb) {
      a[mb].q[0] = *(const uint4*)(smA[pA] + ((ua * 256 + wr + mb * 32 + l31) * 16));
      a[mb].q[1] = *(const uint4*)(smA[pA] + (((ua + 1) * 256 + wr + mb * 32 + l31) * 16));
    }
#pragma unroll
    for (int nb = 0; nb < 4; ++nb) {
      b[nb].q[0] = *(const uint4*)(smB[pB] + ((ua * 128 + nb * 32 + l31) * 16));
      b[nb].q[1] = *(const uint4*)(smB[pB] + (((ua + 1) * 128 + nb * 32 + l31) * 16));
    }
    if (++pB == 3) pB = 0;

#pragma unroll
    for (int mb = 0; mb < 2; ++mb)
#pragma unroll
      for (int nb = 0; nb < 4; ++nb)
        acc[mb][nb] = __builtin_amdgcn_mfma_scale_f32_32x32x64_f8f6f4(
            a[mb].v, b[nb].v, acc[mb][nb],
            0, 0,                      // fp8 e4m3 A and B
            0, 0x7F7F7F7F,             // scale A = 1.0 (E8M0 127 = 2^0)
            0, 0x7F7F7F7F);            // scale B = 1.0

    if (kk == KSTEPS - 1) {
      // Tile done (incl. bias-aug step): l += 2^acc per slot. Bounded values, raw v_exp.
#pragma unroll
      for (int mb = 0; mb < 2; ++mb)
#pragma unroll
        for (int r = 0; r < 16; ++r) {
          l_state[mb * 16 + r] += __builtin_amdgcn_exp2f(acc[mb][0][r])
                                + __builtin_amdgcn_exp2f(acc[mb][1][r])
                                + __builtin_amdgcn_exp2f(acc[mb][2][r])
                                + __builtin_amdgcn_exp2f(acc[mb][3][r]);
        }
#pragma unroll
      for (int mb = 0; mb < 2; ++mb)
#pragma unroll
        for (int nb = 0; nb < 4; ++nb)
#pragma unroll
          for (int i = 0; i < 16; ++i) acc[mb][nb][i] = 0.f;
      kk = 0;
      ++sidx_out;
    } else {
      ++kk;
    }
  }

  // Sum over this wave's 128 cols: butterfly within the 32-lane half.
#pragma unroll
  for (int s = 0; s < 32; ++s) {
    float v = l_state[s];
#pragma unroll
    for (int off = 1; off < 32; off <<= 1) v += __shfl_xor(v, off, 64);
    l_state[s] = v;
  }

  // Each wave owns all cols of its 64 rows -> direct write.
  // C/D 32x32 layout: row = wr + mb*32 + 4*half + (r&3) + 8*(r>>2).
  if (l31 == 0) {
#pragma unroll
    for (int s = 0; s < 32; ++s) {
      const int mb = s >> 4, r = s & 15;
      const int row = wr + mb * 32 + 4 * half + (r & 3) + 8 * (r >> 2);
      partials[(size_t)(row0 + row) * S_SPLITS + blockIdx.y] = l_state[s];
    }
  }
}

// Per-row loss + per-block partial sums. partials hold Σ2^v per (row, split).
__global__ __launch_bounds__(256) void loss_rows(const float* __restrict__ partials,
                                                 const float* __restrict__ tgt_logit,
                                                 const int* __restrict__ target,
                                                 float* __restrict__ bsums) {
  const int r = blockIdx.x * 256 + threadIdx.x;
  float l = 0.f;
#pragma unroll
  for (int s = 0; s < S_SPLITS; ++s) l += partials[(size_t)r * S_SPLITS + s];
  const float lse = LN2 * __log2f(l);
  const bool valid = (target[r] != IGNORE_INDEX);
  float loss = valid ? (lse - tgt_logit[r]) : 0.f;
  float cnt  = valid ? 1.f : 0.f;
  const int lane = threadIdx.x & 63;
  const int w = threadIdx.x >> 6;
#pragma unroll
  for (int off = 32; off >= 1; off >>= 1) {
    loss += __shfl_xor(loss, off, 64);
    cnt  += __shfl_xor(cnt, off, 64);
  }
  __shared__ float sl[4], sc[4];
  if (lane == 0) { sl[w] = loss; sc[w] = cnt; }
  __syncthreads();
  if (threadIdx.x == 0) {
    float S = 0.f, C = 0.f;
    for (int i = 0; i < 4; ++i) { S += sl[i]; C += sc[i]; }
    bsums[blockIdx.x] = S;
    bsums[32 + blockIdx.x] = C;
  }
}

__global__ void finalize(const float* __restrict__ bsums, float* __restrict__ out) {
  const int t = threadIdx.x;  // 64 threads
  float s = (t < 32) ? bsums[t] : 0.f;
  float c = (t < 32) ? bsums[32 + t] : 0.f;
#pragma unroll
  for (int off = 32; off >= 1; off >>= 1) {
    s += __shfl_xor(s, off, 64);
    c += __shfl_xor(c, off, 64);
  }
  if (t == 0) out[0] = s / fmaxf(c, 1.f);
}

extern "C" void kernel_launch(void* const* d_in, const int* in_sizes, int n_in,
                              void* d_out, int out_size, void* d_ws, size_t ws_size,
                              hipStream_t stream) {
  const float* x    = (const float*)d_in[0];
  const float* wgt  = (const float*)d_in[1];
  const float* bias = (const float*)d_in[2];
  const int*   tgt  = (const int*)d_in[3];
  float* out = (float*)d_out;

  char* ws = (char*)d_ws;
  const size_t XS8 = (size_t)UNITS * N_ROWS * 16;   // 8.9 MB fp8 x (68 units)
  const size_t WS8 = (size_t)UNITS * V_PAD * 16;    // 35.7 MB fp8 W
  const size_t PB  = (size_t)N_ROWS * S_SPLITS * 4;
  unsigned char* xs8 = (unsigned char*)ws;
  unsigned char* ws8 = (unsigned char*)(ws + XS8);
  float* partials = (float*)(ws + XS8 + WS8);
  float* tgt_lg   = (float*)(ws + XS8 + WS8 + PB);
  float* bsums    = (float*)(ws + XS8 + WS8 + PB + (size_t)N_ROWS * 4);

  prep_all<<<12352, 256, 0, stream>>>(x, wgt, bias, tgt, xs8, ws8, tgt_lg);
  flce_main<<<dim3(N_ROWS / BM, S_SPLITS), 256, 0, stream>>>(xs8, ws8, partials);
  loss_rows<<<N_ROWS / 256, 256, 0, stream>>>(partials, tgt_lg, tgt, bsums);
  finalize<<<1, 64, 0, stream>>>(bsums, out);
}